// Round 9
// baseline (258.190 us; speedup 1.0000x reference)
//
#include <hip/hip_runtime.h>
#include <stdint.h>

typedef __bf16 bf16x8 __attribute__((ext_vector_type(8)));
typedef float  f32x4  __attribute__((ext_vector_type(4)));
typedef uint16_t u16;

#define MAT_ELEMS (1024 * 1024)

// ---------- helpers ----------

__device__ __forceinline__ u16 to_bf16(float f) {
  union { float f; uint32_t u; } v; v.f = f;
  uint32_t u = v.u;
  uint32_t r = u + 0x7FFFu + ((u >> 16) & 1u);   // RNE
  return (u16)(r >> 16);
}

__device__ __forceinline__ float bf16_to_f32(u16 b) {
  union { uint32_t u; float f; } v; v.u = ((uint32_t)b) << 16;
  return v.f;
}

__device__ __forceinline__ void gll16(const void* g, void* l) {
  __builtin_amdgcn_global_load_lds(
      (__attribute__((address_space(1))) void*)const_cast<void*>(g),
      (__attribute__((address_space(3))) void*)(l),
      16, 0, 0);
}

__device__ __forceinline__ void barrier_pin() {
  __builtin_amdgcn_s_barrier();
  __builtin_amdgcn_sched_barrier(0);
}

__device__ __forceinline__ float fast_sigmoid(float x) {
  x = fminf(fmaxf(x, -30.f), 30.f);
  return 1.0f / (1.0f + __expf(-x));
}

__device__ __forceinline__ float fast_tanh(float x) {
  x = fminf(fmaxf(x, -15.f), 15.f);
  float e = __expf(2.0f * x);
  return (e - 1.0f) / (e + 1.0f);
}

// ---------- prep kernels (unchanged, proven) ----------

struct P8  { const float* p[8]; };
struct P10 { const float* p[10]; };
struct B8  { const float* b[8]; };

__global__ __launch_bounds__(256) void cast8_kernel(P8 s, u16* __restrict__ dst) {
  const float* src = s.p[blockIdx.y];
  u16* d = dst + ((size_t)blockIdx.y << 20);
  int i = (blockIdx.x * 256 + threadIdx.x) * 4;
  f32x4 v = *reinterpret_cast<const f32x4*>(src + i);
  ushort4 o;
  o.x = to_bf16(v[0]); o.y = to_bf16(v[1]);
  o.z = to_bf16(v[2]); o.w = to_bf16(v[3]);
  *reinterpret_cast<ushort4*>(d + i) = o;
}

__global__ __launch_bounds__(256) void transpose_cast_kernel(P10 s, u16* __restrict__ dstbase) {
  __shared__ float tile[32][65];
  const float* src = s.p[blockIdx.z];
  u16* dst = dstbase + ((size_t)blockIdx.z << 20);
  int c0 = blockIdx.x * 64;
  int r0 = blockIdx.y * 32;
  int cl = threadIdx.x & 63;
  int rg = threadIdx.x >> 6;
#pragma unroll
  for (int i = 0; i < 8; ++i) {
    int r = rg + i * 4;
    tile[r][cl] = src[(size_t)(r0 + r) * 1024 + c0 + cl];
  }
  __syncthreads();
  int kl = threadIdx.x & 31;
  int ng = threadIdx.x >> 5;
#pragma unroll
  for (int i = 0; i < 8; ++i) {
    int n = ng + i * 8;
    dst[(size_t)(c0 + n) * 1024 + r0 + kl] = to_bf16(tile[kl][n]);
  }
}

// ---------- 8-phase 256x256 GEMM (m201 template port) ----------
// BM=BN=256, BK=64, 512 thr (8 waves 2Mx4N, 128x64 C each). LDS 128KB dyn:
// A[2buf][2half][128][64] bf16 + B same. Half = op-half (A rows / BT rows).
// Per K-tile: 4 phases; phase q computes C-quadrant, reads {12,4,8,0} b128,
// stages one half-tile (2 gll/thr): q0:(kt+1)A0  q1:(kt+1)A1  q2:(kt+2)B0
// q3:(kt+2)B1 + vmcnt(4) boundary. Slot swizzle: LDS[row][ls] holds global
// 16B-slot ls^(row&7) (involution; pre-swizzled global src, XOR'd read).

#define HALF_U16 8192
#define BUF_U16  16384

__device__ __forceinline__ void stage_half(const u16* __restrict__ src,
                                           u16* __restrict__ dst, int tid) {
#pragma unroll
  for (int s = 0; s < 2; ++s) {
    int idx = s * 512 + tid;       // 0..1023 -> [row 0..127][slot 0..7]
    int row = idx >> 3;
    int gs  = (idx & 7) ^ (row & 7);
    gll16(src + (size_t)row * 1024 + gs * 8, dst + idx * 8);
  }
}

__device__ void gemm8p(const u16* __restrict__ A, const u16* __restrict__ B,
                       int row0, int col0, u16* __restrict__ out, u16* smem)
{
  const int tid  = threadIdx.x;
  const int lane = tid & 63;
  const int w    = tid >> 6;          // 0..7
  const int wm   = w >> 2;            // 0..1 : A half / C 128-row half
  const int wn   = w & 3;             // 0..3 : C 64-col quarter
  const int wh   = wn >> 1;           // B half
  const int r16  = lane & 15;
  const int kg   = lane >> 4;
  const int rsw  = r16 & 7;
  const int brow = (wn & 1) * 64;     // row-in-half of wave's B cols

  u16* Abuf = smem;                   // [buf][half][8192]
  u16* Bbuf = smem + 2 * BUF_U16;

  u16* A0w = Abuf + wm * HALF_U16;               // cur-read bases (wave's half)
  u16* A1w = Abuf + BUF_U16 + wm * HALF_U16;
  u16* B0w = Bbuf + wh * HALF_U16;
  u16* B1w = Bbuf + BUF_U16 + wh * HALF_U16;

  u16* A0d0 = Abuf;            u16* A0d1 = Abuf + HALF_U16;            // stage dsts
  u16* A1d0 = Abuf + BUF_U16;  u16* A1d1 = Abuf + BUF_U16 + HALF_U16;
  u16* B0d0 = Bbuf;            u16* B0d1 = Bbuf + HALF_U16;
  u16* B1d0 = Bbuf + BUF_U16;  u16* B1d1 = Bbuf + BUF_U16 + HALF_U16;

  auto asrc = [&](int kt, int h) { return A + (size_t)(row0 + h * 128) * 1024 + kt * 64; };
  auto bsrc = [&](int kt, int h) { return B + (size_t)(col0 + h * 128) * 1024 + kt * 64; };

  f32x4 acc[8][4];
#pragma unroll
  for (int m = 0; m < 8; ++m)
#pragma unroll
    for (int n = 0; n < 4; ++n) {
      f32x4 z = {0.f, 0.f, 0.f, 0.f};
      acc[m][n] = z;
    }

  // prologue: t0 {A0,A1,B0,B1} -> buf0 ; t1 {B0,B1} -> buf1 ; keep t1 B flying
  stage_half(asrc(0, 0), A0d0, tid); stage_half(asrc(0, 1), A0d1, tid);
  stage_half(bsrc(0, 0), B0d0, tid); stage_half(bsrc(0, 1), B0d1, tid);
  stage_half(bsrc(1, 0), B1d0, tid); stage_half(bsrc(1, 1), B1d1, tid);
  asm volatile("s_waitcnt vmcnt(4)" ::: "memory");
  barrier_pin();

  auto rf = [&](const u16* hb, int rowin, int ks) {
    int slot = (ks * 4 + kg) ^ rsw;
    return *reinterpret_cast<const bf16x8*>(hb + rowin * 64 + slot * 8);
  };

  auto tile = [&](const u16* Ac, const u16* Bc,
                  u16* Ad0, u16* Ad1, u16* Bd0, u16* Bd1,
                  const u16* As0, const u16* As1,
                  const u16* Bs0, const u16* Bs1,
                  bool g1, bool g2, bool vm4)
  {
    bf16x8 aq[4][2], b01[2][2], b23[2][2];
    // ---- q0: reads A-quad0(8) + B nf01(4); stage (kt+1)A0; MFMA quad(0,0)
#pragma unroll
    for (int mf = 0; mf < 4; ++mf) {
      aq[mf][0] = rf(Ac, mf * 16 + r16, 0);
      aq[mf][1] = rf(Ac, mf * 16 + r16, 1);
    }
#pragma unroll
    for (int nf = 0; nf < 2; ++nf) {
      b01[nf][0] = rf(Bc, brow + nf * 16 + r16, 0);
      b01[nf][1] = rf(Bc, brow + nf * 16 + r16, 1);
    }
    if (g1) stage_half(As0, Ad0, tid);
    barrier_pin();
    __builtin_amdgcn_s_setprio(1);
#pragma unroll
    for (int mf = 0; mf < 4; ++mf)
#pragma unroll
      for (int nf = 0; nf < 2; ++nf)
#pragma unroll
        for (int ks = 0; ks < 2; ++ks)
          acc[mf][nf] = __builtin_amdgcn_mfma_f32_16x16x32_bf16(aq[mf][ks], b01[nf][ks], acc[mf][nf], 0, 0, 0);
    __builtin_amdgcn_s_setprio(0);
    barrier_pin();
    // ---- q1: reads B nf23(4); stage (kt+1)A1; MFMA quad(0,1)
#pragma unroll
    for (int nf = 0; nf < 2; ++nf) {
      b23[nf][0] = rf(Bc, brow + (nf + 2) * 16 + r16, 0);
      b23[nf][1] = rf(Bc, brow + (nf + 2) * 16 + r16, 1);
    }
    if (g1) stage_half(As1, Ad1, tid);
    barrier_pin();
    __builtin_amdgcn_s_setprio(1);
#pragma unroll
    for (int mf = 0; mf < 4; ++mf)
#pragma unroll
      for (int nf = 0; nf < 2; ++nf)
#pragma unroll
        for (int ks = 0; ks < 2; ++ks)
          acc[mf][2 + nf] = __builtin_amdgcn_mfma_f32_16x16x32_bf16(aq[mf][ks], b23[nf][ks], acc[mf][2 + nf], 0, 0, 0);
    __builtin_amdgcn_s_setprio(0);
    barrier_pin();
    // ---- q2: reads A-quad1(8); stage (kt+2)B0 (cur buf, freed at q1); MFMA quad(1,0)
#pragma unroll
    for (int mf = 0; mf < 4; ++mf) {
      aq[mf][0] = rf(Ac, 64 + mf * 16 + r16, 0);
      aq[mf][1] = rf(Ac, 64 + mf * 16 + r16, 1);
    }
    if (g2) stage_half(Bs0, Bd0, tid);
    barrier_pin();
    __builtin_amdgcn_s_setprio(1);
#pragma unroll
    for (int mf = 0; mf < 4; ++mf)
#pragma unroll
      for (int nf = 0; nf < 2; ++nf)
#pragma unroll
        for (int ks = 0; ks < 2; ++ks)
          acc[4 + mf][nf] = __builtin_amdgcn_mfma_f32_16x16x32_bf16(aq[mf][ks], b01[nf][ks], acc[4 + mf][nf], 0, 0, 0);
    __builtin_amdgcn_s_setprio(0);
    barrier_pin();
    // ---- q3: stage (kt+2)B1; boundary vmcnt; MFMA quad(1,1)
    if (g2) stage_half(Bs1, Bd1, tid);
    if (vm4) asm volatile("s_waitcnt vmcnt(4)" ::: "memory");
    else     asm volatile("s_waitcnt vmcnt(0)" ::: "memory");
    barrier_pin();
    __builtin_amdgcn_s_setprio(1);
#pragma unroll
    for (int mf = 0; mf < 4; ++mf)
#pragma unroll
      for (int nf = 0; nf < 2; ++nf)
#pragma unroll
        for (int ks = 0; ks < 2; ++ks)
          acc[4 + mf][2 + nf] = __builtin_amdgcn_mfma_f32_16x16x32_bf16(aq[mf][ks], b23[nf][ks], acc[4 + mf][2 + nf], 0, 0, 0);
    __builtin_amdgcn_s_setprio(0);
    barrier_pin();
  };

  for (int i = 0; i < 8; ++i) {
    int kt = 2 * i;
    bool nl = (i < 7);
    // tile kt (buf0): stage (kt+1)A -> buf1, (kt+2)B -> buf0
    tile(A0w, B0w, A1d0, A1d1, B0d0, B0d1,
         asrc(kt + 1, 0), asrc(kt + 1, 1), bsrc(kt + 2, 0), bsrc(kt + 2, 1),
         true, nl, nl);
    // tile kt+1 (buf1): stage (kt+2)A -> buf0, (kt+3)B -> buf1
    tile(A1w, B1w, A0d0, A0d1, B1d0, B1d1,
         asrc(kt + 2, 0), asrc(kt + 2, 1), bsrc(kt + 3, 0), bsrc(kt + 3, 1),
         nl, nl, nl);
  }

  // epilogue: D col = lane&15, row = (lane>>4)*4 + r  [m89-verified]
#pragma unroll
  for (int mf = 0; mf < 8; ++mf) {
#pragma unroll
    for (int r = 0; r < 4; ++r) {
      int row = row0 + wm * 128 + mf * 16 + kg * 4 + r;
#pragma unroll
      for (int nf = 0; nf < 4; ++nf) {
        int col = col0 + wn * 64 + nf * 16 + r16;
        out[(size_t)row * 1024 + col] = to_bf16(acc[mf][nf][r]);
      }
    }
  }
}

// 128 blocks: XCD-chunked so XCD x owns gate x (A+B = 4MB = one L2)
__device__ __forceinline__ void swz_decode(int bx, int& g, int& row0, int& col0) {
  int wg = ((bx & 7) << 4) | (bx >> 3);
  g = wg >> 4;
  int t = wg & 15;                    // 4m x 4n tiles of 256^2
  row0 = (t >> 2) * 256;
  col0 = (t & 3) * 256;
}

__global__ __launch_bounds__(512, 2) void gemm_stage1_kernel(
    const u16* __restrict__ Lb, const u16* __restrict__ xT,
    const u16* __restrict__ hT, u16* __restrict__ Tbuf)
{
  extern __shared__ u16 smem[];
  int g, row0, col0;
  swz_decode(blockIdx.x, g, row0, col0);
  const u16* A = Lb + ((size_t)g << 20);
  const u16* B = (g & 1) ? hT : xT;
  gemm8p(A, B, row0, col0, Tbuf + ((size_t)g << 20), smem);
}

__global__ __launch_bounds__(512, 2) void gemm_stage2_kernel(
    const u16* __restrict__ Tbuf, const u16* __restrict__ RT,
    u16* __restrict__ P)
{
  extern __shared__ u16 smem[];
  int g, row0, col0;
  swz_decode(blockIdx.x, g, row0, col0);
  const u16* A = Tbuf + ((size_t)g << 20);
  const u16* B = RT + ((size_t)g << 20);
  gemm8p(A, B, row0, col0, P + ((size_t)g << 20), smem);
}

// cell: sums gate pairs + biases, applies nonlinearities (unchanged)
__global__ __launch_bounds__(256) void lstm_cell_kernel(
    const u16* __restrict__ P, B8 bp, const float* __restrict__ c,
    float* __restrict__ out)
{
  int i = (blockIdx.x * 256 + threadIdx.x) * 4;
  ushort4 pv[8];
#pragma unroll
  for (int g = 0; g < 8; ++g)
    pv[g] = *reinterpret_cast<const ushort4*>(P + (size_t)g * MAT_ELEMS + i);
  f32x4 bv[8];
#pragma unroll
  for (int g = 0; g < 8; ++g)
    bv[g] = *reinterpret_cast<const f32x4*>(bp.b[g] + i);
  f32x4 cc = *reinterpret_cast<const f32x4*>(c + i);
  f32x4 hn, cn;
#pragma unroll
  for (int j = 0; j < 4; ++j) {
    float pi = bf16_to_f32((&pv[0].x)[j]) + bf16_to_f32((&pv[1].x)[j]) + bv[0][j] + bv[1][j];
    float pf = bf16_to_f32((&pv[2].x)[j]) + bf16_to_f32((&pv[3].x)[j]) + bv[2][j] + bv[3][j];
    float pg = bf16_to_f32((&pv[4].x)[j]) + bf16_to_f32((&pv[5].x)[j]) + bv[4][j] + bv[5][j];
    float po = bf16_to_f32((&pv[6].x)[j]) + bf16_to_f32((&pv[7].x)[j]) + bv[6][j] + bv[7][j];
    float ig = fast_sigmoid(pi);
    float fg = fast_sigmoid(pf);
    float gg = fast_tanh(pg);
    float og = fast_sigmoid(po);
    float cv = fg * cc[j] + ig * gg;
    cn[j] = cv;
    hn[j] = og * fast_tanh(cv);
  }
  *reinterpret_cast<f32x4*>(out + i) = hn;
  *reinterpret_cast<f32x4*>(out + MAT_ELEMS + i) = cn;
}

// ---------- launch ----------

extern "C" void kernel_launch(void* const* d_in, const int* in_sizes, int n_in,
                              void* d_out, int out_size, void* d_ws, size_t ws_size,
                              hipStream_t stream) {
  const float* x = (const float*)d_in[0];
  const float* h = (const float*)d_in[1];
  const float* c = (const float*)d_in[2];

  // ws layout (68 MB):
  u16* Lb   = (u16*)d_ws;                         // 8 x 1M bf16 (16 MB)
  u16* xT   = Lb + ((size_t)8 << 20);             // 2 MB
  u16* hT   = xT + ((size_t)1 << 20);             // 2 MB
  u16* RT   = hT + ((size_t)1 << 20);             // 16 MB
  u16* Tbuf = RT + ((size_t)8 << 20);             // 16 MB
  u16* P    = Tbuf + ((size_t)8 << 20);           // 8 x 1M bf16 (16 MB)

  P8 lp;
  for (int g = 0; g < 8; ++g) lp.p[g] = (const float*)d_in[3 + 3 * g];
  P10 tp;
  tp.p[0] = x; tp.p[1] = h;
  for (int g = 0; g < 8; ++g) tp.p[2 + g] = (const float*)d_in[4 + 3 * g];
  B8 bp;
  for (int g = 0; g < 8; ++g) bp.b[g] = (const float*)d_in[5 + 3 * g];

  cast8_kernel<<<dim3(1024, 8), 256, 0, stream>>>(lp, Lb);
  transpose_cast_kernel<<<dim3(16, 32, 10), 256, 0, stream>>>(tp, xT);
  gemm_stage1_kernel<<<128, 512, 131072, stream>>>(Lb, xT, hT, Tbuf);
  gemm_stage2_kernel<<<128, 512, 131072, stream>>>(Tbuf, RT, P);
  lstm_cell_kernel<<<1024, 256, 0, stream>>>(P, bp, c, (float*)d_out);
}